// Round 1
// baseline (2637.168 us; speedup 1.0000x reference)
//
#include <hip/hip_runtime.h>
#include <math.h>

constexpr int Bc = 2;
constexpr int Sc = 2048;
constexpr int Dc = 1024;
constexpr int Hc = 16;
constexpr int DHc = 64;
constexpr int NTOK = Bc * Sc;          // 4096 tokens
constexpr float ATT_SCALE = 0.125f;    // 1/sqrt(64)

struct QkvArgs { const float* W[6]; const float* bias[6]; float* out[6]; };

// ---------------------------------------------------------------------------
// QKV projection: x[NTOK,1024] @ W[1024,1024] + b  -> out in [b*H+h][s][dh]
// 128x128x16 tile, 256 threads, 8x8 per thread (4+4 split for bank-friendly
// float4 LDS reads). grid.z selects which of the 6 projections.
// ---------------------------------------------------------------------------
__global__ __launch_bounds__(256)
void qkv_gemm(const float* __restrict__ x, QkvArgs args)
{
    const int zi = blockIdx.z;
    const float* __restrict__ W    = args.W[zi];
    const float* __restrict__ bias = args.bias[zi];
    float* __restrict__ out        = args.out[zi];

    __shared__ float As[16][132];  // [k][i]  (A tile transposed)
    __shared__ float Bs[16][132];  // [k][j]

    const int tid = threadIdx.x;
    const int tx = tid & 15;
    const int ty = tid >> 4;
    const int n0 = blockIdx.y * 128;
    const int m0 = blockIdx.x * 128;

    float acc[8][8] = {};

    for (int kt = 0; kt < Dc / 16; ++kt) {
        #pragma unroll
        for (int u = 0; u < 8; ++u) {
            int f = tid + u * 256;
            int r = f >> 4, c = f & 15;
            As[c][r] = x[(size_t)(n0 + r) * Dc + kt * 16 + c];
        }
        #pragma unroll
        for (int u = 0; u < 8; ++u) {
            int f = tid + u * 256;
            int r = f >> 7, c = f & 127;
            Bs[r][c] = W[(size_t)(kt * 16 + r) * Dc + m0 + c];
        }
        __syncthreads();
        #pragma unroll
        for (int kk = 0; kk < 16; ++kk) {
            float a[8], b[8];
            *(float4*)&a[0] = *(const float4*)&As[kk][ty * 4];
            *(float4*)&a[4] = *(const float4*)&As[kk][64 + ty * 4];
            *(float4*)&b[0] = *(const float4*)&Bs[kk][tx * 4];
            *(float4*)&b[4] = *(const float4*)&Bs[kk][64 + tx * 4];
            #pragma unroll
            for (int u = 0; u < 8; ++u)
                #pragma unroll
                for (int v = 0; v < 8; ++v)
                    acc[u][v] += a[u] * b[v];
        }
        __syncthreads();
    }

    // epilogue: write q/k/v layout [b*H+h][s][dh]; each 64-col half is one h
    #pragma unroll
    for (int ub = 0; ub < 2; ++ub) {
        #pragma unroll
        for (int u = 0; u < 4; ++u) {
            int n = n0 + ub * 64 + ty * 4 + u;
            int b = n >> 11;
            int s = n & (Sc - 1);
            #pragma unroll
            for (int vb = 0; vb < 2; ++vb) {
                int h = (m0 >> 6) + vb;
                float4 o;
                o.x = acc[ub * 4 + u][vb * 4 + 0] + bias[h * 64 + tx * 4 + 0];
                o.y = acc[ub * 4 + u][vb * 4 + 1] + bias[h * 64 + tx * 4 + 1];
                o.z = acc[ub * 4 + u][vb * 4 + 2] + bias[h * 64 + tx * 4 + 2];
                o.w = acc[ub * 4 + u][vb * 4 + 3] + bias[h * 64 + tx * 4 + 3];
                size_t base = ((size_t)(b * Hc + h) * Sc + s) * DHc + tx * 4;
                *(float4*)&out[base] = o;
            }
        }
    }
}

// ---------------------------------------------------------------------------
// Flash attention, fp32. One block = one (branch, b*H+h, 64-row q tile).
// Per k-tile: S=Q·K^T in regs -> staged as P^T in LDS (aliases K tile) ->
// per-row online softmax -> O += P·V. Everything b128 / conflict-free.
// ---------------------------------------------------------------------------
__global__ __launch_bounds__(256)
void attn_kernel(const float* __restrict__ q1, const float* __restrict__ k1,
                 const float* __restrict__ v1, float* __restrict__ o1,
                 const float* __restrict__ q2, const float* __restrict__ k2,
                 const float* __restrict__ v2, float* __restrict__ o2)
{
    const int qt = blockIdx.x;   // 0..31 q tile
    const int bh = blockIdx.y;   // 0..31 (b*16+h)
    const int br = blockIdx.z;   // branch
    const float* __restrict__ q = br ? q2 : q1;
    const float* __restrict__ k = br ? k2 : k1;
    const float* __restrict__ v = br ? v2 : v1;
    float* __restrict__ o = br ? o2 : o1;

    __shared__ float qst[64][68];  // q^T  [d][i]
    __shared__ float kpt[64][68];  // k^T  [d][j]; reused as p^T [j][i]
    __shared__ float vs[64][68];   // v    [j][d]
    __shared__ float mrow[64], lrow[64], arow[64];

    const int tid = threadIdx.x;
    const size_t hb = (size_t)bh * Sc * DHc;

    #pragma unroll
    for (int u = 0; u < 16; ++u) {
        int f = tid + u * 256;
        qst[f & 63][f >> 6] = q[hb + (size_t)qt * 4096 + f];
    }
    if (tid < 64) { mrow[tid] = -INFINITY; lrow[tid] = 0.0f; }

    const int i0 = (tid >> 4) * 4;   // q-row group
    const int j0 = (tid & 15) * 4;   // k-col group (phase1) / d group (phase4)

    float oacc[4][4] = {};

    for (int kt = 0; kt < Sc / 64; ++kt) {
        __syncthreads();  // previous iter done with kpt/vs
        #pragma unroll
        for (int u = 0; u < 16; ++u) {
            int f = tid + u * 256;
            int r = f >> 6, c = f & 63;
            kpt[c][r] = k[hb + (size_t)kt * 4096 + f];
            vs[r][c]  = v[hb + (size_t)kt * 4096 + f];
        }
        __syncthreads();

        // phase1: s[i0+u][j0+v] = q_i . k_j
        float sacc[4][4] = {};
        #pragma unroll 8
        for (int d = 0; d < 64; ++d) {
            float a[4], bfr[4];
            *(float4*)&a[0]   = *(const float4*)&qst[d][i0];
            *(float4*)&bfr[0] = *(const float4*)&kpt[d][j0];
            #pragma unroll
            for (int u = 0; u < 4; ++u)
                #pragma unroll
                for (int v = 0; v < 4; ++v)
                    sacc[u][v] += a[u] * bfr[v];
        }
        __syncthreads();
        // phase2: store scaled scores transposed: kpt[j][i] = s[i][j]*scale
        #pragma unroll
        for (int v = 0; v < 4; ++v) {
            float4 t;
            t.x = sacc[0][v] * ATT_SCALE;
            t.y = sacc[1][v] * ATT_SCALE;
            t.z = sacc[2][v] * ATT_SCALE;
            t.w = sacc[3][v] * ATT_SCALE;
            *(float4*)&kpt[j0 + v][i0] = t;
        }
        __syncthreads();
        // phase3: online softmax, one thread per q row (column scan of p^T,
        // lanes hit distinct banks)
        if (tid < 64) {
            float m_old = mrow[tid];
            float tmax = m_old;
            #pragma unroll 8
            for (int j = 0; j < 64; ++j) tmax = fmaxf(tmax, kpt[j][tid]);
            float alpha = __expf(m_old - tmax);   // 0 on first tile (-inf)
            float l = lrow[tid] * alpha;
            #pragma unroll 8
            for (int j = 0; j < 64; ++j) {
                float p = __expf(kpt[j][tid] - tmax);
                kpt[j][tid] = p;
                l += p;
            }
            mrow[tid] = tmax; lrow[tid] = l; arow[tid] = alpha;
        }
        __syncthreads();
        // phase4: O = alpha*O + P.V   (o[i0+u][j0+v])
        #pragma unroll
        for (int u = 0; u < 4; ++u) {
            float al = arow[i0 + u];
            #pragma unroll
            for (int v = 0; v < 4; ++v) oacc[u][v] *= al;
        }
        #pragma unroll 8
        for (int j = 0; j < 64; ++j) {
            float a[4], bfr[4];
            *(float4*)&a[0]   = *(const float4*)&kpt[j][i0];  // p^T[j][i]
            *(float4*)&bfr[0] = *(const float4*)&vs[j][j0];   // v[j][d]
            #pragma unroll
            for (int u = 0; u < 4; ++u)
                #pragma unroll
                for (int v = 0; v < 4; ++v)
                    oacc[u][v] += a[u] * bfr[v];
        }
    }

    // epilogue: o stored [n][h*64+dh] for the following GEMM
    const int b = bh >> 4, h = bh & 15;
    #pragma unroll
    for (int u = 0; u < 4; ++u) {
        int s = qt * 64 + i0 + u;
        float linv = 1.0f / lrow[i0 + u];
        float4 t;
        t.x = oacc[u][0] * linv; t.y = oacc[u][1] * linv;
        t.z = oacc[u][2] * linv; t.w = oacc[u][3] * linv;
        size_t base = ((size_t)(b * Sc + s)) * Dc + h * 64 + j0;
        *(float4*)&o[base] = t;
    }
}

// ---------------------------------------------------------------------------
// Combine: adiff = o1@Wo1 - lam*(o2@Wo2) + (bo1 - lam*bo2)
// Single K=2048 GEMM: first 64 k-tiles from o1/Wo1, next 64 from o2/(-lam*Wo2)
// ---------------------------------------------------------------------------
__global__ __launch_bounds__(256)
void combine_gemm(const float* __restrict__ o1b, const float* __restrict__ o2b,
                  const float* __restrict__ Wo1, const float* __restrict__ Wo2,
                  const float* __restrict__ bo1, const float* __restrict__ bo2,
                  const int* __restrict__ layer_idx, const float* __restrict__ lamp,
                  float* __restrict__ outb)
{
    __shared__ float As[16][132];
    __shared__ float Bs[16][132];
    const int tid = threadIdx.x;
    const int tx = tid & 15, ty = tid >> 4;
    const int n0 = blockIdx.y * 128, m0 = blockIdx.x * 128;

    const float lf = (float)layer_idx[0];
    const float lam = fminf(fmaxf(
        (0.8f - 0.6f * __expf(-0.3f * fmaxf(lf - 1.0f, 0.0f))) * lamp[0],
        0.1f), 0.9f);

    float acc[8][8] = {};
    for (int kt = 0; kt < 128; ++kt) {
        const float* __restrict__ A  = (kt < 64) ? o1b : o2b;
        const float* __restrict__ Bw = (kt < 64) ? Wo1 : Wo2;
        const float bsc = (kt < 64) ? 1.0f : -lam;
        const int ko = (kt & 63) * 16;
        #pragma unroll
        for (int u = 0; u < 8; ++u) {
            int f = tid + u * 256;
            int r = f >> 4, c = f & 15;
            As[c][r] = A[(size_t)(n0 + r) * Dc + ko + c];
        }
        #pragma unroll
        for (int u = 0; u < 8; ++u) {
            int f = tid + u * 256;
            int r = f >> 7, c = f & 127;
            Bs[r][c] = bsc * Bw[(size_t)(ko + r) * Dc + m0 + c];
        }
        __syncthreads();
        #pragma unroll
        for (int kk = 0; kk < 16; ++kk) {
            float a[8], b[8];
            *(float4*)&a[0] = *(const float4*)&As[kk][ty * 4];
            *(float4*)&a[4] = *(const float4*)&As[kk][64 + ty * 4];
            *(float4*)&b[0] = *(const float4*)&Bs[kk][tx * 4];
            *(float4*)&b[4] = *(const float4*)&Bs[kk][64 + tx * 4];
            #pragma unroll
            for (int u = 0; u < 8; ++u)
                #pragma unroll
                for (int v = 0; v < 8; ++v)
                    acc[u][v] += a[u] * b[v];
        }
        __syncthreads();
    }

    #pragma unroll
    for (int ub = 0; ub < 2; ++ub) {
        #pragma unroll
        for (int u = 0; u < 4; ++u) {
            int n = n0 + ub * 64 + ty * 4 + u;
            #pragma unroll
            for (int vb = 0; vb < 2; ++vb) {
                int j = m0 + vb * 64 + tx * 4;
                float4 t;
                t.x = acc[ub*4+u][vb*4+0] + bo1[j+0] - lam * bo2[j+0];
                t.y = acc[ub*4+u][vb*4+1] + bo1[j+1] - lam * bo2[j+1];
                t.z = acc[ub*4+u][vb*4+2] + bo1[j+2] - lam * bo2[j+2];
                t.w = acc[ub*4+u][vb*4+3] + bo1[j+3] - lam * bo2[j+3];
                *(float4*)&outb[(size_t)n * Dc + j] = t;
            }
        }
    }
}

// ---------------------------------------------------------------------------
// Final: out = adiff @ Wp + bp
// ---------------------------------------------------------------------------
__global__ __launch_bounds__(256)
void final_gemm(const float* __restrict__ A, const float* __restrict__ W,
                const float* __restrict__ bias, float* __restrict__ outb)
{
    __shared__ float As[16][132];
    __shared__ float Bs[16][132];
    const int tid = threadIdx.x;
    const int tx = tid & 15, ty = tid >> 4;
    const int n0 = blockIdx.y * 128, m0 = blockIdx.x * 128;

    float acc[8][8] = {};
    for (int kt = 0; kt < Dc / 16; ++kt) {
        #pragma unroll
        for (int u = 0; u < 8; ++u) {
            int f = tid + u * 256;
            int r = f >> 4, c = f & 15;
            As[c][r] = A[(size_t)(n0 + r) * Dc + kt * 16 + c];
        }
        #pragma unroll
        for (int u = 0; u < 8; ++u) {
            int f = tid + u * 256;
            int r = f >> 7, c = f & 127;
            Bs[r][c] = W[(size_t)(kt * 16 + r) * Dc + m0 + c];
        }
        __syncthreads();
        #pragma unroll
        for (int kk = 0; kk < 16; ++kk) {
            float a[8], b[8];
            *(float4*)&a[0] = *(const float4*)&As[kk][ty * 4];
            *(float4*)&a[4] = *(const float4*)&As[kk][64 + ty * 4];
            *(float4*)&b[0] = *(const float4*)&Bs[kk][tx * 4];
            *(float4*)&b[4] = *(const float4*)&Bs[kk][64 + tx * 4];
            #pragma unroll
            for (int u = 0; u < 8; ++u)
                #pragma unroll
                for (int v = 0; v < 8; ++v)
                    acc[u][v] += a[u] * b[v];
        }
        __syncthreads();
    }

    #pragma unroll
    for (int ub = 0; ub < 2; ++ub) {
        #pragma unroll
        for (int u = 0; u < 4; ++u) {
            int n = n0 + ub * 64 + ty * 4 + u;
            #pragma unroll
            for (int vb = 0; vb < 2; ++vb) {
                int j = m0 + vb * 64 + tx * 4;
                float4 t;
                t.x = acc[ub*4+u][vb*4+0] + bias[j+0];
                t.y = acc[ub*4+u][vb*4+1] + bias[j+1];
                t.z = acc[ub*4+u][vb*4+2] + bias[j+2];
                t.w = acc[ub*4+u][vb*4+3] + bias[j+3];
                *(float4*)&outb[(size_t)n * Dc + j] = t;
            }
        }
    }
}

// ---------------------------------------------------------------------------
extern "C" void kernel_launch(void* const* d_in, const int* in_sizes, int n_in,
                              void* d_out, int out_size, void* d_ws, size_t ws_size,
                              hipStream_t stream)
{
    const float* x    = (const float*)d_in[0];
    const int*   lidx = (const int*)  d_in[1];
    const float* lamp = (const float*)d_in[2];
    const float* Wq1  = (const float*)d_in[3];
    const float* Wk1  = (const float*)d_in[4];
    const float* Wv1  = (const float*)d_in[5];
    const float* Wo1  = (const float*)d_in[6];
    const float* bq1  = (const float*)d_in[7];
    const float* bk1  = (const float*)d_in[8];
    const float* bv1  = (const float*)d_in[9];
    const float* bo1  = (const float*)d_in[10];
    const float* Wq2  = (const float*)d_in[11];
    const float* Wk2  = (const float*)d_in[12];
    const float* Wv2  = (const float*)d_in[13];
    const float* Wo2  = (const float*)d_in[14];
    const float* bq2  = (const float*)d_in[15];
    const float* bk2  = (const float*)d_in[16];
    const float* bv2  = (const float*)d_in[17];
    const float* bo2  = (const float*)d_in[18];
    const float* Wp   = (const float*)d_in[19];
    const float* bp   = (const float*)d_in[20];

    float* ws = (float*)d_ws;
    const size_t BUF = (size_t)NTOK * Dc;   // 4M floats = 16 MB
    float* q1  = ws + 0 * BUF;
    float* k1  = ws + 1 * BUF;
    float* v1  = ws + 2 * BUF;
    float* q2  = ws + 3 * BUF;
    float* k2  = ws + 4 * BUF;
    float* v2  = ws + 5 * BUF;
    float* o1b = ws + 6 * BUF;
    float* o2b = ws + 7 * BUF;
    float* ad  = ws + 8 * BUF;

    QkvArgs qa;
    qa.W[0] = Wq1; qa.bias[0] = bq1; qa.out[0] = q1;
    qa.W[1] = Wk1; qa.bias[1] = bk1; qa.out[1] = k1;
    qa.W[2] = Wv1; qa.bias[2] = bv1; qa.out[2] = v1;
    qa.W[3] = Wq2; qa.bias[3] = bq2; qa.out[3] = q2;
    qa.W[4] = Wk2; qa.bias[4] = bk2; qa.out[4] = k2;
    qa.W[5] = Wv2; qa.bias[5] = bv2; qa.out[5] = v2;

    qkv_gemm<<<dim3(Dc / 128, NTOK / 128, 6), dim3(256), 0, stream>>>(x, qa);
    attn_kernel<<<dim3(Sc / 64, Bc * Hc, 2), dim3(256), 0, stream>>>(
        q1, k1, v1, o1b, q2, k2, v2, o2b);
    combine_gemm<<<dim3(Dc / 128, NTOK / 128), dim3(256), 0, stream>>>(
        o1b, o2b, Wo1, Wo2, bo1, bo2, lidx, lamp, ad);
    final_gemm<<<dim3(Dc / 128, NTOK / 128), dim3(256), 0, stream>>>(
        ad, Wp, bp, (float*)d_out);
}

// Round 2
// 588.385 us; speedup vs baseline: 4.4820x; 4.4820x over previous
//
#include <hip/hip_runtime.h>
#include <math.h>

typedef unsigned short u16;
typedef __attribute__((ext_vector_type(8))) short bf16x8;
typedef __attribute__((ext_vector_type(4))) float f32x4;
typedef __attribute__((ext_vector_type(4))) unsigned short u16x4;
typedef __attribute__((ext_vector_type(8))) unsigned short u16x8;

constexpr int Sq = 2048, Dm = 1024, Hh = 16, DH = 64;
constexpr int NT = 4096;                 // tokens (B*S)
constexpr float ATT_SCALE = 0.125f;      // 1/sqrt(64)
constexpr float LOG2E = 1.44269504f;

__device__ __forceinline__ u16 f2bf(float f) {
    unsigned u = __float_as_uint(f);
    return (u16)((u + 0x7FFF + ((u >> 16) & 1)) >> 16);
}

// async global->LDS, 16B per lane; LDS base is wave-uniform, HW adds lane*16
__device__ __forceinline__ void async16(u16* lds, const u16* g) {
    __builtin_amdgcn_global_load_lds(
        (const __attribute__((address_space(1))) unsigned int*)g,
        (__attribute__((address_space(3))) unsigned int*)lds, 16, 0, 0);
}

__device__ __forceinline__ float lam_of(const int* lidx, const float* lamp) {
    float lf = (float)lidx[0];
    float init = 0.8f - 0.6f * __expf(-0.3f * fmaxf(lf - 1.0f, 0.0f));
    return fminf(fmaxf(init * lamp[0], 0.1f), 0.9f);
}

// ---------------------------------------------------------------------------
// Shared 128x128 MFMA GEMM mainloop.  A:[M][K] bf16 row-major, Bt:[N][K] bf16.
// LDS tiles [128 rows][64 k] with 16B-chunk XOR swizzle (chunk ^ (row&7)):
// keeps global_load_lds contiguity AND makes ds_read_b128 frag loads 2-way
// (free).  4 waves, each 64x64 = 4x4 mfma_f32_16x16x32_bf16 tiles.
// ---------------------------------------------------------------------------
__device__ __forceinline__ void gemm_tile_128(
    const u16* __restrict__ A, const u16* __restrict__ Bt, int K,
    int aRow0, int bCol0, u16* As, u16* Bs, f32x4 acc[4][4])
{
    const int tid = threadIdx.x;
    const int w = tid >> 6, lane = tid & 63;
    const int ln = lane & 15, quad = lane >> 4;
    const int wm = (w >> 1) * 64, wn = (w & 1) * 64;
    const int l3 = lane & 7, lr8 = lane >> 3;

    for (int kt = 0; kt < K; kt += 64) {
        __syncthreads();                      // prev-iter reads complete
        #pragma unroll
        for (int c0 = 0; c0 < 4; ++c0) {
            int c = w * 4 + c0;               // 16 calls, 8 rows each
            int lr = c * 8 + lr8;
            int sc = l3 ^ (lr & 7);           // swizzled source chunk
            async16(As + c * 512, A + (size_t)(aRow0 + lr) * K + kt + sc * 8);
            async16(Bs + c * 512, Bt + (size_t)(bCol0 + lr) * K + kt + sc * 8);
        }
        __syncthreads();                      // drains vmcnt (staging done)
        #pragma unroll
        for (int kc = 0; kc < 2; ++kc) {
            bf16x8 af[4], bfr[4];
            #pragma unroll
            for (int mt = 0; mt < 4; ++mt)
                af[mt] = *(const bf16x8*)(As + (wm + mt * 16 + ln) * 64 +
                                          (((kc * 4 + quad) ^ (ln & 7)) * 8));
            #pragma unroll
            for (int nt = 0; nt < 4; ++nt)
                bfr[nt] = *(const bf16x8*)(Bs + (wn + nt * 16 + ln) * 64 +
                                           (((kc * 4 + quad) ^ (ln & 7)) * 8));
            #pragma unroll
            for (int mt = 0; mt < 4; ++mt)
                #pragma unroll
                for (int nt = 0; nt < 4; ++nt)
                    acc[mt][nt] = __builtin_amdgcn_mfma_f32_16x16x32_bf16(
                        af[mt], bfr[nt], acc[mt][nt], 0, 0, 0);
        }
    }
}

// ---------------------------------------------------------------------------
// fp32 -> bf16 flat convert (x)
// ---------------------------------------------------------------------------
__global__ __launch_bounds__(256)
void convert_x(const float* __restrict__ x, u16* __restrict__ xb)
{
    int i = (blockIdx.x * 256 + threadIdx.x) * 4;
    float4 v = *(const float4*)(x + i);
    u16x4 o;
    o.x = f2bf(v.x); o.y = f2bf(v.y); o.z = f2bf(v.z); o.w = f2bf(v.w);
    *(u16x4*)(xb + i) = o;
}

// ---------------------------------------------------------------------------
// Weight transpose-convert: src fp32 [1024 k][1024 n] -> dst bf16 [n][k],
// optional scale (z==7 -> -lambda for Wo2).  64x64 tiles via LDS.
// ---------------------------------------------------------------------------
struct TcP { const float* src[9]; u16* dst[9]; int ld[9]; int coff[9]; };

__global__ __launch_bounds__(256)
void wconv(TcP p, const int* __restrict__ lidx, const float* __restrict__ lamp)
{
    __shared__ float t[64][65];
    const int z = blockIdx.z;
    const float scale = (z == 7) ? -lam_of(lidx, lamp) : 1.0f;
    const float* __restrict__ src = p.src[z];
    u16* __restrict__ dst = p.dst[z];
    const int kb = blockIdx.y * 64, nb = blockIdx.x * 64;
    const int tid = threadIdx.x;
    {
        int r = tid >> 2, cs = (tid & 3) * 16;
        #pragma unroll
        for (int j4 = 0; j4 < 16; j4 += 4) {
            float4 v = *(const float4*)&src[(size_t)(kb + r) * 1024 + nb + cs + j4];
            t[r][cs + j4 + 0] = v.x; t[r][cs + j4 + 1] = v.y;
            t[r][cs + j4 + 2] = v.z; t[r][cs + j4 + 3] = v.w;
        }
    }
    __syncthreads();
    {
        int n = tid >> 2, ks = (tid & 3) * 16;
        u16x8 a, b;
        #pragma unroll
        for (int j = 0; j < 8; ++j) a[j] = f2bf(scale * t[ks + j][n]);
        #pragma unroll
        for (int j = 0; j < 8; ++j) b[j] = f2bf(scale * t[ks + 8 + j][n]);
        u16* o = &dst[(size_t)(nb + n) * p.ld[z] + p.coff[z] + kb + ks];
        *(u16x8*)o = a;
        *(u16x8*)(o + 8) = b;
    }
}

// ---------------------------------------------------------------------------
// QKV projection GEMM: xb[4096][1024] @ Wt[z]^T + b -> [bh][s][64] bf16
// ---------------------------------------------------------------------------
struct QkvP { const u16* Wt[6]; const float* bias[6]; u16* out[6]; };

__global__ __launch_bounds__(256, 3)
void qkv_mfma(const u16* __restrict__ xb, QkvP p)
{
    __shared__ u16 As[128 * 64], Bs[128 * 64];
    const int z = blockIdx.z;
    const int aRow0 = blockIdx.y * 128, nCol0 = blockIdx.x * 128;
    f32x4 acc[4][4] = {};
    gemm_tile_128(xb, p.Wt[z], 1024, aRow0, nCol0, As, Bs, acc);

    const float* __restrict__ bias = p.bias[z];
    u16* __restrict__ out = p.out[z];
    const int tid = threadIdx.x, w = tid >> 6, lane = tid & 63;
    const int ln = lane & 15, quad = lane >> 4;
    const int wm = (w >> 1) * 64, wn = (w & 1) * 64;
    #pragma unroll
    for (int mt = 0; mt < 4; ++mt) {
        #pragma unroll
        for (int nt = 0; nt < 4; ++nt) {
            int gn = nCol0 + wn + nt * 16 + ln;
            int h = gn >> 6, dh = gn & 63;
            float bv = bias[gn];
            #pragma unroll
            for (int r = 0; r < 4; ++r) {
                int gm = aRow0 + wm + mt * 16 + quad * 4 + r;
                int b = gm >> 11, s = gm & (Sq - 1);
                out[((size_t)(b * Hh + h) * Sq + s) * DH + dh] =
                    f2bf(acc[mt][nt][r] + bv);
            }
        }
    }
}

// ---------------------------------------------------------------------------
// v [bh][2048][64] -> vt [bh][64][2048]  (bf16 transpose, LDS tiled)
// ---------------------------------------------------------------------------
__global__ __launch_bounds__(256)
void vtrans(const u16* __restrict__ v1, u16* __restrict__ vt1,
            const u16* __restrict__ v2, u16* __restrict__ vt2)
{
    __shared__ u16 t[64][72];
    const u16* __restrict__ src = blockIdx.z ? v2 : v1;
    u16* __restrict__ dst = blockIdx.z ? vt2 : vt1;
    const int bh = blockIdx.y, st = blockIdx.x * 64;
    const int tid = threadIdx.x;
    {
        int r = tid >> 2, cs = (tid & 3) * 16;
        const u16* s = &src[((size_t)bh * Sq + st + r) * DH + cs];
        *(u16x8*)&t[r][cs] = *(const u16x8*)s;
        *(u16x8*)&t[r][cs + 8] = *(const u16x8*)(s + 8);
    }
    __syncthreads();
    {
        int dn = tid >> 2, ss = (tid & 3) * 16;
        u16x8 a, b;
        #pragma unroll
        for (int j = 0; j < 8; ++j) a[j] = t[ss + j][dn];
        #pragma unroll
        for (int j = 0; j < 8; ++j) b[j] = t[ss + 8 + j][dn];
        u16* o = &dst[((size_t)bh * DH + dn) * Sq + st + ss];
        *(u16x8*)o = a;
        *(u16x8*)(o + 8) = b;
    }
}

// ---------------------------------------------------------------------------
// Flash attention, bf16 MFMA.  Block = (q-tile 128, bh, branch); 4 waves,
// each 32 q-rows.  Q frags hoisted to regs; P round-trips LDS (C->A layout).
// Writes O into ocat[4096][2048] at col br*1024 + h*64 + d.
// ---------------------------------------------------------------------------
__global__ __launch_bounds__(256, 3)
void attn_mfma(const u16* __restrict__ q1, const u16* __restrict__ k1,
               const u16* __restrict__ vt1,
               const u16* __restrict__ q2, const u16* __restrict__ k2,
               const u16* __restrict__ vt2, u16* __restrict__ ocat)
{
    __shared__ u16 SP[128 * 64];   // Q at init, then per-wave P regions
    __shared__ u16 Ks[64 * 64];
    __shared__ u16 Vs[64 * 64];    // V^T tile: rows=d, cols=key

    const int qt = blockIdx.x, bh = blockIdx.y, br = blockIdx.z;
    const u16* __restrict__ q = br ? q2 : q1;
    const u16* __restrict__ k = br ? k2 : k1;
    const u16* __restrict__ vt = br ? vt2 : vt1;

    const int tid = threadIdx.x, w = tid >> 6, lane = tid & 63;
    const int ln = lane & 15, quad = lane >> 4;
    const int l3 = lane & 7, lr8 = lane >> 3;
    const size_t qkBase = (size_t)bh * Sq * DH;
    const size_t vtBase = (size_t)bh * DH * Sq;

    // stage Q (wave w loads exactly its own rows w*32..w*32+31)
    #pragma unroll
    for (int c0 = 0; c0 < 4; ++c0) {
        int c = w * 4 + c0;
        int lr = c * 8 + lr8;
        int sc = l3 ^ (lr & 7);
        async16(SP + c * 512, q + qkBase + (size_t)(qt * 128 + lr) * DH + sc * 8);
    }
    __syncthreads();

    bf16x8 qf[2][2];
    #pragma unroll
    for (int mt = 0; mt < 2; ++mt)
        #pragma unroll
        for (int kc = 0; kc < 2; ++kc)
            qf[mt][kc] = *(const bf16x8*)(SP + (w * 32 + mt * 16 + ln) * 64 +
                                          (((kc * 4 + quad) ^ (ln & 7)) * 8));

    f32x4 oacc[2][4] = {};
    float mprev[2][4], lsum[2][4];
    #pragma unroll
    for (int mt = 0; mt < 2; ++mt)
        #pragma unroll
        for (int r = 0; r < 4; ++r) { mprev[mt][r] = -3.0e38f; lsum[mt][r] = 0.f; }

    for (int kt = 0; kt < Sq / 64; ++kt) {
        __syncthreads();                       // all reads of prev Ks/Vs done
        #pragma unroll
        for (int c0 = 0; c0 < 2; ++c0) {
            int c = w * 2 + c0;
            int lr = c * 8 + lr8;
            int sc = l3 ^ (lr & 7);
            async16(Ks + c * 512, k + qkBase + (size_t)(kt * 64 + lr) * DH + sc * 8);
            async16(Vs + c * 512, vt + vtBase + (size_t)lr * Sq + kt * 64 + sc * 8);
        }
        __syncthreads();                       // staging visible

        // S = Q K^T   (C-layout: row=quad*4+reg is q-row, col=ln is key)
        f32x4 sacc[2][4] = {};
        #pragma unroll
        for (int kc = 0; kc < 2; ++kc) {
            bf16x8 kf[4];
            #pragma unroll
            for (int nt = 0; nt < 4; ++nt)
                kf[nt] = *(const bf16x8*)(Ks + (nt * 16 + ln) * 64 +
                                          (((kc * 4 + quad) ^ (ln & 7)) * 8));
            #pragma unroll
            for (int mt = 0; mt < 2; ++mt)
                #pragma unroll
                for (int nt = 0; nt < 4; ++nt)
                    sacc[mt][nt] = __builtin_amdgcn_mfma_f32_16x16x32_bf16(
                        qf[mt][kc], kf[nt], sacc[mt][nt], 0, 0, 0);
        }

        // online softmax per q-row; write P (bf16) into this wave's LDS region
        #pragma unroll
        for (int mt = 0; mt < 2; ++mt) {
            #pragma unroll
            for (int r = 0; r < 4; ++r) {
                float sl[4];
                #pragma unroll
                for (int nt = 0; nt < 4; ++nt) sl[nt] = sacc[mt][nt][r] * ATT_SCALE;
                float mx = fmaxf(fmaxf(sl[0], sl[1]), fmaxf(sl[2], sl[3]));
                mx = fmaxf(mx, __shfl_xor(mx, 1));
                mx = fmaxf(mx, __shfl_xor(mx, 2));
                mx = fmaxf(mx, __shfl_xor(mx, 4));
                mx = fmaxf(mx, __shfl_xor(mx, 8));
                float mi = fmaxf(mprev[mt][r], mx);
                float alpha = exp2f((mprev[mt][r] - mi) * LOG2E);
                float psum = 0.f;
                int m = mt * 16 + quad * 4 + r;
                #pragma unroll
                for (int nt = 0; nt < 4; ++nt) {
                    float pv = exp2f((sl[nt] - mi) * LOG2E);
                    psum += pv;
                    int col = nt * 16 + ln;
                    SP[w * 2048 + m * 64 + (((col >> 3) ^ (m & 7)) * 8) + (col & 7)] =
                        f2bf(pv);
                }
                psum += __shfl_xor(psum, 1);
                psum += __shfl_xor(psum, 2);
                psum += __shfl_xor(psum, 4);
                psum += __shfl_xor(psum, 8);
                lsum[mt][r] = lsum[mt][r] * alpha + psum;
                mprev[mt][r] = mi;
                #pragma unroll
                for (int dt = 0; dt < 4; ++dt) oacc[mt][dt][r] *= alpha;
            }
        }
        __syncthreads();                       // P writes drained (conservative)

        // O += P V   (A=P rows=q, B=V^T rows=d)
        #pragma unroll
        for (int kc = 0; kc < 2; ++kc) {
            bf16x8 pf[2], vf[4];
            #pragma unroll
            for (int mt = 0; mt < 2; ++mt)
                pf[mt] = *(const bf16x8*)(SP + w * 2048 + (mt * 16 + ln) * 64 +
                                          (((kc * 4 + quad) ^ (ln & 7)) * 8));
            #pragma unroll
            for (int dt = 0; dt < 4; ++dt)
                vf[dt] = *(const bf16x8*)(Vs + (dt * 16 + ln) * 64 +
                                          (((kc * 4 + quad) ^ (ln & 7)) * 8));
            #pragma unroll
            for (int mt = 0; mt < 2; ++mt)
                #pragma unroll
                for (int dt = 0; dt < 4; ++dt)
                    oacc[mt][dt] = __builtin_amdgcn_mfma_f32_16x16x32_bf16(
                        pf[mt], vf[dt], oacc[mt][dt], 0, 0, 0);
        }
    }

    const int b = bh >> 4, h = bh & 15;
    #pragma unroll
    for (int mt = 0; mt < 2; ++mt) {
        #pragma unroll
        for (int r = 0; r < 4; ++r) {
            float inv = 1.0f / lsum[mt][r];
            int s = qt * 128 + w * 32 + mt * 16 + quad * 4 + r;
            size_t rowb = (size_t)(b * Sq + s) * 2048 + br * 1024 + h * 64;
            #pragma unroll
            for (int dt = 0; dt < 4; ++dt)
                ocat[rowb + dt * 16 + ln] = f2bf(oacc[mt][dt][r] * inv);
        }
    }
}

// ---------------------------------------------------------------------------
// Combine: adiff = ocat[4096][2048] @ Wcmb^T + (bo1 - lam*bo2)  -> bf16
// (Wcmb rows n: [Wo1^T | (-lam Wo2)^T], K=2048)
// ---------------------------------------------------------------------------
__global__ __launch_bounds__(256, 3)
void combine_mfma(const u16* __restrict__ ocat, const u16* __restrict__ Wcmb,
                  const float* __restrict__ bo1, const float* __restrict__ bo2,
                  const int* __restrict__ lidx, const float* __restrict__ lamp,
                  u16* __restrict__ adiff)
{
    __shared__ u16 As[128 * 64], Bs[128 * 64];
    const int aRow0 = blockIdx.y * 128, nCol0 = blockIdx.x * 128;
    f32x4 acc[4][4] = {};
    gemm_tile_128(ocat, Wcmb, 2048, aRow0, nCol0, As, Bs, acc);

    const float lam = lam_of(lidx, lamp);
    const int tid = threadIdx.x, w = tid >> 6, lane = tid & 63;
    const int ln = lane & 15, quad = lane >> 4;
    const int wm = (w >> 1) * 64, wn = (w & 1) * 64;
    #pragma unroll
    for (int mt = 0; mt < 4; ++mt) {
        #pragma unroll
        for (int nt = 0; nt < 4; ++nt) {
            int gn = nCol0 + wn + nt * 16 + ln;
            float bv = bo1[gn] - lam * bo2[gn];
            #pragma unroll
            for (int r = 0; r < 4; ++r) {
                int gm = aRow0 + wm + mt * 16 + quad * 4 + r;
                adiff[(size_t)gm * 1024 + gn] = f2bf(acc[mt][nt][r] + bv);
            }
        }
    }
}

// ---------------------------------------------------------------------------
// Final: out = adiff @ Wp^T + bp   (fp32 out)
// ---------------------------------------------------------------------------
__global__ __launch_bounds__(256, 3)
void final_mfma(const u16* __restrict__ adiff, const u16* __restrict__ Wpt,
                const float* __restrict__ bp, float* __restrict__ outb)
{
    __shared__ u16 As[128 * 64], Bs[128 * 64];
    const int aRow0 = blockIdx.y * 128, nCol0 = blockIdx.x * 128;
    f32x4 acc[4][4] = {};
    gemm_tile_128(adiff, Wpt, 1024, aRow0, nCol0, As, Bs, acc);

    const int tid = threadIdx.x, w = tid >> 6, lane = tid & 63;
    const int ln = lane & 15, quad = lane >> 4;
    const int wm = (w >> 1) * 64, wn = (w & 1) * 64;
    #pragma unroll
    for (int mt = 0; mt < 4; ++mt) {
        #pragma unroll
        for (int nt = 0; nt < 4; ++nt) {
            int gn = nCol0 + wn + nt * 16 + ln;
            float bv = bp[gn];
            #pragma unroll
            for (int r = 0; r < 4; ++r) {
                int gm = aRow0 + wm + mt * 16 + quad * 4 + r;
                outb[(size_t)gm * 1024 + gn] = acc[mt][nt][r] + bv;
            }
        }
    }
}

// ---------------------------------------------------------------------------
extern "C" void kernel_launch(void* const* d_in, const int* in_sizes, int n_in,
                              void* d_out, int out_size, void* d_ws, size_t ws_size,
                              hipStream_t stream)
{
    const float* x    = (const float*)d_in[0];
    const int*   lidx = (const int*)  d_in[1];
    const float* lamp = (const float*)d_in[2];
    const float* Wq1  = (const float*)d_in[3];
    const float* Wk1  = (const float*)d_in[4];
    const float* Wv1  = (const float*)d_in[5];
    const float* Wo1  = (const float*)d_in[6];
    const float* bq1  = (const float*)d_in[7];
    const float* bk1  = (const float*)d_in[8];
    const float* bv1  = (const float*)d_in[9];
    const float* bo1  = (const float*)d_in[10];
    const float* Wq2  = (const float*)d_in[11];
    const float* Wk2  = (const float*)d_in[12];
    const float* Wv2  = (const float*)d_in[13];
    const float* Wo2  = (const float*)d_in[14];
    const float* bq2  = (const float*)d_in[15];
    const float* bk2  = (const float*)d_in[16];
    const float* bv2  = (const float*)d_in[17];
    const float* bo2  = (const float*)d_in[18];
    const float* Wp   = (const float*)d_in[19];
    const float* bp   = (const float*)d_in[20];

    char* wsb = (char*)d_ws;
    const size_t MB = 1 << 20;
    u16* xb   = (u16*)(wsb + 0 * MB);          // 8 MB
    u16* Wt0  = (u16*)(wsb + 8 * MB);          // 6 x 2 MB
    u16* Wcmb = (u16*)(wsb + 20 * MB);         // 4 MB  [1024][2048]
    u16* Wpt  = (u16*)(wsb + 24 * MB);         // 2 MB
    u16* qb1  = (u16*)(wsb + 26 * MB);         // each 8 MB
    u16* kb1  = (u16*)(wsb + 34 * MB);
    u16* vb1  = (u16*)(wsb + 42 * MB);
    u16* qb2  = (u16*)(wsb + 50 * MB);
    u16* kb2  = (u16*)(wsb + 58 * MB);
    u16* vb2  = (u16*)(wsb + 66 * MB);
    u16* vtb1 = (u16*)(wsb + 74 * MB);
    u16* vtb2 = (u16*)(wsb + 82 * MB);
    u16* ocat = (u16*)(wsb + 90 * MB);         // 16 MB [4096][2048]
    u16* adif = (u16*)(wsb + 106 * MB);        // 8 MB

    convert_x<<<dim3(NT * Dm / 1024), dim3(256), 0, stream>>>(x, xb);

    TcP tp;
    const float* wsrc[9] = {Wq1, Wk1, Wv1, Wq2, Wk2, Wv2, Wo1, Wo2, Wp};
    for (int i = 0; i < 9; ++i) tp.src[i] = wsrc[i];
    for (int i = 0; i < 6; ++i) { tp.dst[i] = Wt0 + (size_t)i * 1024 * 1024; tp.ld[i] = 1024; tp.coff[i] = 0; }
    tp.dst[6] = Wcmb; tp.ld[6] = 2048; tp.coff[6] = 0;
    tp.dst[7] = Wcmb; tp.ld[7] = 2048; tp.coff[7] = 1024;
    tp.dst[8] = Wpt;  tp.ld[8] = 1024; tp.coff[8] = 0;
    wconv<<<dim3(16, 16, 9), dim3(256), 0, stream>>>(tp, lidx, lamp);

    QkvP qp;
    qp.Wt[0] = Wt0 + 0 * 1048576; qp.bias[0] = bq1; qp.out[0] = qb1;
    qp.Wt[1] = Wt0 + 1 * 1048576; qp.bias[1] = bk1; qp.out[1] = kb1;
    qp.Wt[2] = Wt0 + 2 * 1048576; qp.bias[2] = bv1; qp.out[2] = vb1;
    qp.Wt[3] = Wt0 + 3 * 1048576; qp.bias[3] = bq2; qp.out[3] = qb2;
    qp.Wt[4] = Wt0 + 4 * 1048576; qp.bias[4] = bk2; qp.out[4] = kb2;
    qp.Wt[5] = Wt0 + 5 * 1048576; qp.bias[5] = bv2; qp.out[5] = vb2;
    qkv_mfma<<<dim3(8, 32, 6), dim3(256), 0, stream>>>(xb, qp);

    vtrans<<<dim3(32, 32, 2), dim3(256), 0, stream>>>(vb1, vtb1, vb2, vtb2);

    attn_mfma<<<dim3(16, 32, 2), dim3(256), 0, stream>>>(
        qb1, kb1, vtb1, qb2, kb2, vtb2, ocat);

    combine_mfma<<<dim3(8, 32), dim3(256), 0, stream>>>(
        ocat, Wcmb, bo1, bo2, lidx, lamp, adif);

    final_mfma<<<dim3(8, 32), dim3(256), 0, stream>>>(
        adif, Wpt, bp, (float*)d_out);
}

// Round 3
// 377.328 us; speedup vs baseline: 6.9891x; 1.5593x over previous
//
#include <hip/hip_runtime.h>
#include <math.h>

typedef unsigned short u16;
typedef __attribute__((ext_vector_type(8))) short bf16x8;
typedef __attribute__((ext_vector_type(4))) float f32x4;
typedef __attribute__((ext_vector_type(4))) unsigned short u16x4;
typedef __attribute__((ext_vector_type(8))) unsigned short u16x8;

constexpr int Sq = 2048, Dm = 1024, Hh = 16, DH = 64;
constexpr int NT = 4096;                 // tokens (B*S)
constexpr float SEXP = 0.125f * 1.44269504f;   // scale * log2(e)

__device__ __forceinline__ u16 f2bf(float f) {
    unsigned u = __float_as_uint(f);
    return (u16)((u + 0x7FFF + ((u >> 16) & 1)) >> 16);
}

// async global->LDS, 16B per lane; LDS base is wave-uniform, HW adds lane*16
__device__ __forceinline__ void async16(u16* lds, const u16* g) {
    __builtin_amdgcn_global_load_lds(
        (const __attribute__((address_space(1))) unsigned int*)g,
        (__attribute__((address_space(3))) unsigned int*)lds, 16, 0, 0);
}

__device__ __forceinline__ float lam_of(const int* lidx, const float* lamp) {
    float lf = (float)lidx[0];
    float init = 0.8f - 0.6f * __expf(-0.3f * fmaxf(lf - 1.0f, 0.0f));
    return fminf(fmaxf(init * lamp[0], 0.1f), 0.9f);
}

// ---------------------------------------------------------------------------
// 128x128 MFMA GEMM mainloop (unchanged from R2).  A:[M][K], Bt:[N][K] bf16.
// ---------------------------------------------------------------------------
__device__ __forceinline__ void gemm_tile_128(
    const u16* __restrict__ A, const u16* __restrict__ Bt, int K,
    int aRow0, int bCol0, u16* As, u16* Bs, f32x4 acc[4][4])
{
    const int tid = threadIdx.x;
    const int w = tid >> 6, lane = tid & 63;
    const int ln = lane & 15, quad = lane >> 4;
    const int wm = (w >> 1) * 64, wn = (w & 1) * 64;
    const int l3 = lane & 7, lr8 = lane >> 3;

    for (int kt = 0; kt < K; kt += 64) {
        __syncthreads();
        #pragma unroll
        for (int c0 = 0; c0 < 4; ++c0) {
            int c = w * 4 + c0;
            int lr = c * 8 + lr8;
            int sc = l3 ^ (lr & 7);
            async16(As + c * 512, A + (size_t)(aRow0 + lr) * K + kt + sc * 8);
            async16(Bs + c * 512, Bt + (size_t)(bCol0 + lr) * K + kt + sc * 8);
        }
        __syncthreads();
        #pragma unroll
        for (int kc = 0; kc < 2; ++kc) {
            bf16x8 af[4], bfr[4];
            #pragma unroll
            for (int mt = 0; mt < 4; ++mt)
                af[mt] = *(const bf16x8*)(As + (wm + mt * 16 + ln) * 64 +
                                          (((kc * 4 + quad) ^ (ln & 7)) * 8));
            #pragma unroll
            for (int nt = 0; nt < 4; ++nt)
                bfr[nt] = *(const bf16x8*)(Bs + (wn + nt * 16 + ln) * 64 +
                                           (((kc * 4 + quad) ^ (ln & 7)) * 8));
            #pragma unroll
            for (int mt = 0; mt < 4; ++mt)
                #pragma unroll
                for (int nt = 0; nt < 4; ++nt)
                    acc[mt][nt] = __builtin_amdgcn_mfma_f32_16x16x32_bf16(
                        af[mt], bfr[nt], acc[mt][nt], 0, 0, 0);
        }
    }
}

// ---------------------------------------------------------------------------
// 64x128 MFMA GEMM mainloop (for combine/final: 2x the blocks -> 2/CU)
// ---------------------------------------------------------------------------
__device__ __forceinline__ void gemm_tile_64(
    const u16* __restrict__ A, const u16* __restrict__ Bt, int K,
    int aRow0, int bCol0, u16* As, u16* Bs, f32x4 acc[2][4])
{
    const int tid = threadIdx.x;
    const int w = tid >> 6, lane = tid & 63;
    const int ln = lane & 15, quad = lane >> 4;
    const int wm = (w >> 1) * 32, wn = (w & 1) * 64;
    const int l3 = lane & 7, lr8 = lane >> 3;

    for (int kt = 0; kt < K; kt += 64) {
        __syncthreads();
        #pragma unroll
        for (int c0 = 0; c0 < 2; ++c0) {        // A: 64 rows = 8 calls
            int c = w * 2 + c0;
            int lr = c * 8 + lr8;
            int sc = l3 ^ (lr & 7);
            async16(As + c * 512, A + (size_t)(aRow0 + lr) * K + kt + sc * 8);
        }
        #pragma unroll
        for (int c0 = 0; c0 < 4; ++c0) {        // B: 128 rows = 16 calls
            int c = w * 4 + c0;
            int lr = c * 8 + lr8;
            int sc = l3 ^ (lr & 7);
            async16(Bs + c * 512, Bt + (size_t)(bCol0 + lr) * K + kt + sc * 8);
        }
        __syncthreads();
        #pragma unroll
        for (int kc = 0; kc < 2; ++kc) {
            bf16x8 af[2], bfr[4];
            #pragma unroll
            for (int mt = 0; mt < 2; ++mt)
                af[mt] = *(const bf16x8*)(As + (wm + mt * 16 + ln) * 64 +
                                          (((kc * 4 + quad) ^ (ln & 7)) * 8));
            #pragma unroll
            for (int nt = 0; nt < 4; ++nt)
                bfr[nt] = *(const bf16x8*)(Bs + (wn + nt * 16 + ln) * 64 +
                                           (((kc * 4 + quad) ^ (ln & 7)) * 8));
            #pragma unroll
            for (int mt = 0; mt < 2; ++mt)
                #pragma unroll
                for (int nt = 0; nt < 4; ++nt)
                    acc[mt][nt] = __builtin_amdgcn_mfma_f32_16x16x32_bf16(
                        af[mt], bfr[nt], acc[mt][nt], 0, 0, 0);
        }
    }
}

// ---------------------------------------------------------------------------
__global__ __launch_bounds__(256)
void convert_x(const float* __restrict__ x, u16* __restrict__ xb)
{
    int i = (blockIdx.x * 256 + threadIdx.x) * 4;
    float4 v = *(const float4*)(x + i);
    u16x4 o;
    o.x = f2bf(v.x); o.y = f2bf(v.y); o.z = f2bf(v.z); o.w = f2bf(v.w);
    *(u16x4*)(xb + i) = o;
}

// ---------------------------------------------------------------------------
// Weight transpose-convert (unchanged)
// ---------------------------------------------------------------------------
struct TcP { const float* src[9]; u16* dst[9]; int ld[9]; int coff[9]; };

__global__ __launch_bounds__(256)
void wconv(TcP p, const int* __restrict__ lidx, const float* __restrict__ lamp)
{
    __shared__ float t[64][65];
    const int z = blockIdx.z;
    const float scale = (z == 7) ? -lam_of(lidx, lamp) : 1.0f;
    const float* __restrict__ src = p.src[z];
    u16* __restrict__ dst = p.dst[z];
    const int kb = blockIdx.y * 64, nb = blockIdx.x * 64;
    const int tid = threadIdx.x;
    {
        int r = tid >> 2, cs = (tid & 3) * 16;
        #pragma unroll
        for (int j4 = 0; j4 < 16; j4 += 4) {
            float4 v = *(const float4*)&src[(size_t)(kb + r) * 1024 + nb + cs + j4];
            t[r][cs + j4 + 0] = v.x; t[r][cs + j4 + 1] = v.y;
            t[r][cs + j4 + 2] = v.z; t[r][cs + j4 + 3] = v.w;
        }
    }
    __syncthreads();
    {
        int n = tid >> 2, ks = (tid & 3) * 16;
        u16x8 a, b;
        #pragma unroll
        for (int j = 0; j < 8; ++j) a[j] = f2bf(scale * t[ks + j][n]);
        #pragma unroll
        for (int j = 0; j < 8; ++j) b[j] = f2bf(scale * t[ks + 8 + j][n]);
        u16* o = &dst[(size_t)(nb + n) * p.ld[z] + p.coff[z] + kb + ks];
        *(u16x8*)o = a;
        *(u16x8*)(o + 8) = b;
    }
}

// ---------------------------------------------------------------------------
// QKV projection.  Q -> standard [bh][s][64].  K,V -> MFMA-fragment order:
//   K tile (32 keys): frag f=kc*2+nt (nt=key16, kc=d32): elem = f*512+L*8+j,
//     L=((dh>>3)&3)*16+(s&15), j=dh&7
//   V tile: frag dt=d16: k_idx=(s&15)*2+((s>>4)&1) (interleaved keys);
//     elem = dt*512 + ((k_idx>>3)*16+(dh&15))*8 + (k_idx&7)
// ---------------------------------------------------------------------------
struct QkvP { const u16* Wt[6]; const float* bias[6]; u16* out[6]; };

__global__ __launch_bounds__(256, 3)
void qkv_mfma(const u16* __restrict__ xb, QkvP p)
{
    __shared__ u16 As[128 * 64], Bs[128 * 64];
    const int z = blockIdx.z;
    const int type = (z < 3) ? z : z - 3;   // 0=q 1=k 2=v
    const int aRow0 = blockIdx.y * 128, nCol0 = blockIdx.x * 128;
    f32x4 acc[4][4] = {};
    gemm_tile_128(xb, p.Wt[z], 1024, aRow0, nCol0, As, Bs, acc);

    const float* __restrict__ bias = p.bias[z];
    u16* __restrict__ out = p.out[z];
    const int tid = threadIdx.x, w = tid >> 6, lane = tid & 63;
    const int ln = lane & 15, quad = lane >> 4;
    const int wm = (w >> 1) * 64, wn = (w & 1) * 64;
    #pragma unroll
    for (int mt = 0; mt < 4; ++mt) {
        #pragma unroll
        for (int nt = 0; nt < 4; ++nt) {
            int gn = nCol0 + wn + nt * 16 + ln;
            int h = gn >> 6, dh = gn & 63;
            float bv = bias[gn];
            #pragma unroll
            for (int r = 0; r < 4; ++r) {
                int gm = aRow0 + wm + mt * 16 + quad * 4 + r;
                int b = gm >> 11, s = gm & (Sq - 1);
                size_t bh = (size_t)(b * Hh + h);
                u16 val = f2bf(acc[mt][nt][r] + bv);
                size_t idx;
                if (type == 0) {
                    idx = bh * 131072 + (size_t)s * 64 + dh;
                } else if (type == 1) {
                    idx = bh * 131072 + (size_t)(s >> 5) * 2048 +
                          (size_t)((dh >> 5) * 2 + ((s >> 4) & 1)) * 512 +
                          (size_t)(((dh >> 3) & 3) * 16 + (s & 15)) * 8 + (dh & 7);
                } else {
                    int kidx = ((s & 15) * 2) + ((s >> 4) & 1);
                    idx = bh * 131072 + (size_t)(s >> 5) * 2048 +
                          (size_t)(dh >> 4) * 512 +
                          (size_t)((kidx >> 3) * 16 + (dh & 15)) * 8 + (kidx & 7);
                }
                out[idx] = val;
            }
        }
    }
}

// ---------------------------------------------------------------------------
// Flash attention, barrier-free main loop.
// Block: 64 q-rows shared by 4 waves; wave w owns key-tiles {w, w+4, ...}
// (32 keys each).  K/V B-frags loaded DIRECTLY from fragged global layout
// (coalesced dwordx4).  No-max softmax; row-sum l via MFMA with ones-B.
// P round-trips per-wave LDS (16 packed b32 writes / 4 b128 reads).
// O/l partials merged across waves once at the end.
// ---------------------------------------------------------------------------
__global__ __launch_bounds__(256, 2)
void attn_mfma(const u16* __restrict__ q1, const u16* __restrict__ kf1,
               const u16* __restrict__ vf1,
               const u16* __restrict__ q2, const u16* __restrict__ kf2,
               const u16* __restrict__ vf2, u16* __restrict__ ocat)
{
    // LDS: main loop: P regions, per wave 5120 B (64 rows x 80 B).
    // end: O partials 3 x 17408 B (64 q x 68 f32) + l 3 x 256 B (union w/ P).
    __shared__ __align__(16) char smem[3 * 17408 + 768];

    const int qblk = blockIdx.x, bh = blockIdx.y, br = blockIdx.z;
    const u16* __restrict__ q  = br ? q2  : q1;
    const u16* __restrict__ kf = br ? kf2 : kf1;
    const u16* __restrict__ vf = br ? vf2 : vf1;

    const int tid = threadIdx.x, w = tid >> 6, lane = tid & 63;
    const int ln = lane & 15, quad = lane >> 4;
    char* Pbase = smem + w * 5120;

    // hoist Q A-frags (A[m=q][k=d]; lane: m=ln, k=quad*8+j)
    const u16* qbase = q + (size_t)bh * 131072 + (size_t)(qblk * 64) * 64;
    bf16x8 qf[4][2];
    #pragma unroll
    for (int mt = 0; mt < 4; ++mt)
        #pragma unroll
        for (int kc = 0; kc < 2; ++kc)
            qf[mt][kc] = *(const bf16x8*)(qbase + (mt * 16 + ln) * 64 +
                                          kc * 32 + quad * 8);

    bf16x8 ones;
    #pragma unroll
    for (int j = 0; j < 8; ++j) ones[j] = (short)0x3F80;

    f32x4 oacc[4][4] = {};
    f32x4 lacc[4] = {};

    const u16* kbase = kf + (size_t)bh * 131072 + lane * 8;
    const u16* vbase = vf + (size_t)bh * 131072 + lane * 8;

    for (int it = 0; it < 16; ++it) {
        const int kt = it * 4 + w;
        const u16* kp = kbase + (size_t)kt * 2048;
        const u16* vp = vbase + (size_t)kt * 2048;

        bf16x8 kfr[2][2], vfr[4];
        #pragma unroll
        for (int kc = 0; kc < 2; ++kc)
            #pragma unroll
            for (int nt = 0; nt < 2; ++nt)
                kfr[nt][kc] = *(const bf16x8*)(kp + (kc * 2 + nt) * 512);
        #pragma unroll
        for (int dt = 0; dt < 4; ++dt)
            vfr[dt] = *(const bf16x8*)(vp + dt * 512);

        // S = Q K^T  (C: row=q-local, col=key-local)
        f32x4 sacc[4][2] = {};
        #pragma unroll
        for (int kc = 0; kc < 2; ++kc)
            #pragma unroll
            for (int mt = 0; mt < 4; ++mt)
                #pragma unroll
                for (int nt = 0; nt < 2; ++nt)
                    sacc[mt][nt] = __builtin_amdgcn_mfma_f32_16x16x32_bf16(
                        qf[mt][kc], kfr[nt][kc], sacc[mt][nt], 0, 0, 0);

        // no-max softmax: p = 2^(s*scale*log2e); pack pairs (nt0,nt1) ->
        // one dword (k_idx = 2*ln + nt), round-half-up, write swizzled
        #pragma unroll
        for (int mt = 0; mt < 4; ++mt) {
            #pragma unroll
            for (int r = 0; r < 4; ++r) {
                float p0 = exp2f(sacc[mt][0][r] * SEXP);
                float p1 = exp2f(sacc[mt][1][r] * SEXP);
                unsigned a  = __float_as_uint(p0) + 0x8000u;
                unsigned b2 = __float_as_uint(p1) + 0x8000u;
                unsigned pk = __builtin_amdgcn_perm(b2, a, 0x07060302);
                int row = mt * 16 + quad * 4 + r;
                *(unsigned*)(Pbase + row * 80 + (((ln >> 2) ^ r) << 4) +
                             ((ln & 3) << 2)) = pk;
            }
        }

        // O += P V ; l += P . 1   (per-wave LDS, same-wave ordering only)
        #pragma unroll
        for (int mt = 0; mt < 4; ++mt) {
            bf16x8 pf = *(const bf16x8*)(Pbase + (mt * 16 + ln) * 80 +
                                         ((quad ^ (ln & 3)) << 4));
            lacc[mt] = __builtin_amdgcn_mfma_f32_16x16x32_bf16(
                pf, ones, lacc[mt], 0, 0, 0);
            #pragma unroll
            for (int dt = 0; dt < 4; ++dt)
                oacc[mt][dt] = __builtin_amdgcn_mfma_f32_16x16x32_bf16(
                    pf, vfr[dt], oacc[mt][dt], 0, 0, 0);
        }
    }

    // ---- merge the 4 waves' partials ----
    __syncthreads();                       // all P reads done; LDS reused
    char* lbase = smem + 3 * 17408;
    if (w < 3) {
        char* ob = smem + w * 17408;
        #pragma unroll
        for (int mt = 0; mt < 4; ++mt) {
            #pragma unroll
            for (int dt = 0; dt < 4; ++dt)
                #pragma unroll
                for (int r = 0; r < 4; ++r)
                    *(float*)(ob + (mt * 16 + quad * 4 + r) * 272 +
                              (dt * 16 + ln) * 4) = oacc[mt][dt][r];
            if (ln == 0)
                #pragma unroll
                for (int r = 0; r < 4; ++r)
                    *(float*)(lbase + w * 256 + (mt * 16 + quad * 4 + r) * 4) =
                        lacc[mt][r];
        }
    }
    __syncthreads();
    if (w == 3) {
        #pragma unroll
        for (int mt = 0; mt < 4; ++mt) {
            #pragma unroll
            for (int dt = 0; dt < 4; ++dt)
                #pragma unroll
                for (int r = 0; r < 4; ++r) {
                    float* pp = (float*)(smem + (mt * 16 + quad * 4 + r) * 272 +
                                         (dt * 16 + ln) * 4);
                    *pp += oacc[mt][dt][r];
                }
            if (ln == 0)
                #pragma unroll
                for (int r = 0; r < 4; ++r) {
                    float* pp = (float*)(lbase + (mt * 16 + quad * 4 + r) * 4);
                    *pp += lacc[mt][r];
                }
        }
    }
    __syncthreads();

    // ---- reduce 3 regions, normalize, store bf16 ----
    {
        int qr = tid >> 2, dg = tid & 3;
        float lt = *(float*)(lbase + qr * 4) + *(float*)(lbase + 256 + qr * 4) +
                   *(float*)(lbase + 512 + qr * 4);
        float inv = 1.0f / lt;
        float vals[16];
        #pragma unroll
        for (int c = 0; c < 4; ++c) {
            f32x4 v0 = *(f32x4*)(smem + 0 * 17408 + qr * 272 + dg * 64 + c * 16);
            f32x4 v1 = *(f32x4*)(smem + 1 * 17408 + qr * 272 + dg * 64 + c * 16);
            f32x4 v2 = *(f32x4*)(smem + 2 * 17408 + qr * 272 + dg * 64 + c * 16);
            #pragma unroll
            for (int i = 0; i < 4; ++i)
                vals[c * 4 + i] = (v0[i] + v1[i] + v2[i]) * inv;
        }
        int token = (bh >> 4) * 2048 + qblk * 64 + qr;
        size_t base = (size_t)token * 2048 + br * 1024 + (bh & 15) * 64 + dg * 16;
        u16x8 o0, o1;
        #pragma unroll
        for (int i = 0; i < 8; ++i) { o0[i] = f2bf(vals[i]); o1[i] = f2bf(vals[8 + i]); }
        *(u16x8*)(ocat + base) = o0;
        *(u16x8*)(ocat + base + 8) = o1;
    }
}

// ---------------------------------------------------------------------------
// Combine: adiff = ocat[4096][2048] @ Wcmb^T + (bo1 - lam*bo2)  -> bf16
// ---------------------------------------------------------------------------
__global__ __launch_bounds__(256, 4)
void combine_mfma(const u16* __restrict__ ocat, const u16* __restrict__ Wcmb,
                  const float* __restrict__ bo1, const float* __restrict__ bo2,
                  const int* __restrict__ lidx, const float* __restrict__ lamp,
                  u16* __restrict__ adiff)
{
    __shared__ u16 As[64 * 64], Bs[128 * 64];
    const int aRow0 = blockIdx.y * 64, nCol0 = blockIdx.x * 128;
    f32x4 acc[2][4] = {};
    gemm_tile_64(ocat, Wcmb, 2048, aRow0, nCol0, As, Bs, acc);

    const float lam = lam_of(lidx, lamp);
    const int tid = threadIdx.x, w = tid >> 6, lane = tid & 63;
    const int ln = lane & 15, quad = lane >> 4;
    const int wm = (w >> 1) * 32, wn = (w & 1) * 64;
    #pragma unroll
    for (int mt = 0; mt < 2; ++mt) {
        #pragma unroll
        for (int nt = 0; nt < 4; ++nt) {
            int gn = nCol0 + wn + nt * 16 + ln;
            float bv = bo1[gn] - lam * bo2[gn];
            #pragma unroll
            for (int r = 0; r < 4; ++r) {
                int gm = aRow0 + wm + mt * 16 + quad * 4 + r;
                adiff[(size_t)gm * 1024 + gn] = f2bf(acc[mt][nt][r] + bv);
            }
        }
    }
}

// ---------------------------------------------------------------------------
// Final: out = adiff @ Wp^T + bp   (fp32 out)
// ---------------------------------------------------------------------------
__global__ __launch_bounds__(256, 4)
void final_mfma(const u16* __restrict__ adiff, const u16* __restrict__ Wpt,
                const float* __restrict__ bp, float* __restrict__ outb)
{
    __shared__ u16 As[64 * 64], Bs[128 * 64];
    const int aRow0 = blockIdx.y * 64, nCol0 = blockIdx.x * 128;
    f32x4 acc[2][4] = {};
    gemm_tile_64(adiff, Wpt, 1024, aRow0, nCol0, As, Bs, acc);

    const int tid = threadIdx.x, w = tid >> 6, lane = tid & 63;
    const int ln = lane & 15, quad = lane >> 4;
    const int wm = (w >> 1) * 32, wn = (w & 1) * 64;
    #pragma unroll
    for (int mt = 0; mt < 2; ++mt) {
        #pragma unroll
        for (int nt = 0; nt < 4; ++nt) {
            int gn = nCol0 + wn + nt * 16 + ln;
            float bv = bp[gn];
            #pragma unroll
            for (int r = 0; r < 4; ++r) {
                int gm = aRow0 + wm + mt * 16 + quad * 4 + r;
                outb[(size_t)gm * 1024 + gn] = acc[mt][nt][r] + bv;
            }
        }
    }
}

// ---------------------------------------------------------------------------
extern "C" void kernel_launch(void* const* d_in, const int* in_sizes, int n_in,
                              void* d_out, int out_size, void* d_ws, size_t ws_size,
                              hipStream_t stream)
{
    const float* x    = (const float*)d_in[0];
    const int*   lidx = (const int*)  d_in[1];
    const float* lamp = (const float*)d_in[2];
    const float* Wq1  = (const float*)d_in[3];
    const float* Wk1  = (const float*)d_in[4];
    const float* Wv1  = (const float*)d_in[5];
    const float* Wo1  = (const float*)d_in[6];
    const float* bq1  = (const float*)d_in[7];
    const float* bk1  = (const float*)d_in[8];
    const float* bv1  = (const float*)d_in[9];
    const float* bo1  = (const float*)d_in[10];
    const float* Wq2  = (const float*)d_in[11];
    const float* Wk2  = (const float*)d_in[12];
    const float* Wv2  = (const float*)d_in[13];
    const float* Wo2  = (const float*)d_in[14];
    const float* bq2  = (const float*)d_in[15];
    const float* bk2  = (const float*)d_in[16];
    const float* bv2  = (const float*)d_in[17];
    const float* bo2  = (const float*)d_in[18];
    const float* Wp   = (const float*)d_in[19];
    const float* bp   = (const float*)d_in[20];

    char* wsb = (char*)d_ws;
    const size_t MB = 1 << 20;
    u16* xb   = (u16*)(wsb + 0 * MB);          // 8 MB
    u16* Wt0  = (u16*)(wsb + 8 * MB);          // 6 x 2 MB
    u16* Wcmb = (u16*)(wsb + 20 * MB);         // 4 MB
    u16* Wpt  = (u16*)(wsb + 24 * MB);         // 2 MB
    u16* qb1  = (u16*)(wsb + 26 * MB);         // 8 MB each
    u16* kb1  = (u16*)(wsb + 34 * MB);         // fragged
    u16* vb1  = (u16*)(wsb + 42 * MB);         // fragged
    u16* qb2  = (u16*)(wsb + 50 * MB);
    u16* kb2  = (u16*)(wsb + 58 * MB);
    u16* vb2  = (u16*)(wsb + 66 * MB);
    u16* ocat = (u16*)(wsb + 74 * MB);         // 16 MB
    u16* adif = (u16*)(wsb + 90 * MB);         // 8 MB

    convert_x<<<dim3(NT * Dm / 1024), dim3(256), 0, stream>>>(x, xb);

    TcP tp;
    const float* wsrc[9] = {Wq1, Wk1, Wv1, Wq2, Wk2, Wv2, Wo1, Wo2, Wp};
    for (int i = 0; i < 9; ++i) tp.src[i] = wsrc[i];
    for (int i = 0; i < 6; ++i) { tp.dst[i] = Wt0 + (size_t)i * 1024 * 1024; tp.ld[i] = 1024; tp.coff[i] = 0; }
    tp.dst[6] = Wcmb; tp.ld[6] = 2048; tp.coff[6] = 0;
    tp.dst[7] = Wcmb; tp.ld[7] = 2048; tp.coff[7] = 1024;
    tp.dst[8] = Wpt;  tp.ld[8] = 1024; tp.coff[8] = 0;
    wconv<<<dim3(16, 16, 9), dim3(256), 0, stream>>>(tp, lidx, lamp);

    QkvP qp;
    qp.Wt[0] = Wt0 + 0 * 1048576; qp.bias[0] = bq1; qp.out[0] = qb1;
    qp.Wt[1] = Wt0 + 1 * 1048576; qp.bias[1] = bk1; qp.out[1] = kb1;
    qp.Wt[2] = Wt0 + 2 * 1048576; qp.bias[2] = bv1; qp.out[2] = vb1;
    qp.Wt[3] = Wt0 + 3 * 1048576; qp.bias[3] = bq2; qp.out[3] = qb2;
    qp.Wt[4] = Wt0 + 4 * 1048576; qp.bias[4] = bk2; qp.out[4] = kb2;
    qp.Wt[5] = Wt0 + 5 * 1048576; qp.bias[5] = bv2; qp.out[5] = vb2;
    qkv_mfma<<<dim3(8, 32, 6), dim3(256), 0, stream>>>(xb, qp);

    attn_mfma<<<dim3(32, 32, 2), dim3(256), 0, stream>>>(
        qb1, kb1, vb1, qb2, kb2, vb2, ocat);

    combine_mfma<<<dim3(8, 64), dim3(256), 0, stream>>>(
        ocat, Wcmb, bo1, bo2, lidx, lamp, adif);

    final_mfma<<<dim3(8, 64), dim3(256), 0, stream>>>(
        adif, Wpt, bp, (float*)d_out);
}